// Round 10
// baseline (554.971 us; speedup 1.0000x reference)
//
#include <hip/hip_runtime.h>

// Problem constants (fixed by the reference's setup_inputs)
#define BATCH   256
#define N_PER   4096
#define EMBED   16
#define HID     32
#define NOTE    64
#define LSTM_D  64
#define T_LEN   128
#define VOCAB   200
#define HSTR    (BATCH * HID)     // floats per node row-group (tree-inner layout)

// meta header (ints)
#define MH_CNT   0    // [0..4] internal count at level 1..5
#define MH_PBASE 5    // [5..9] PLIST base of level 1..5
// meta arrays (ints)
#define OFF_PLIST 64
#define OFF_COFF  (OFF_PLIST + N_PER)      // N_PER+1 entries, node-indexed
#define OFF_CIDX  (OFF_COFF + N_PER + 1)   // child node ids
// ws byte offsets
#define EAW_BYTE    (1024 * 1024)          // [VOCAB][HID]
#define EBW_BYTE    (EAW_BYTE + 32 * 1024)
#define LEAFTA_BYTE (EAW_BYTE + 64 * 1024) // [VOCAB][HID] fused leaf tables
#define LEAFTB_BYTE (EAW_BYTE + 96 * 1024)
#define BF_BYTE     (EAW_BYTE + 128 * 1024)// [HID] fused leaf bias
#define FNPRE_BYTE  (1536 * 1024)          // [BATCH][HID]
#define PTRPRE_BYTE (2ull * 1024 * 1024)   // [BATCH*T_LEN][HID]
#define H_BYTE      (8ull * 1024 * 1024)   // [node][BATCH][HID] = 134 MB

struct KParams {
    const int *kind, *height, *parent, *tok_a, *tok_b, *ptr_time;
    const float *first_notes, *lstm_out, *embedding;
    const float *leaf_w1, *leaf_b1, *leaf_w2, *leaf_b2;
    const float *node_w, *node_b, *ptr_w, *ptr_b;
    const float *ff_w1, *ff_b1, *ff_w2, *ff_b2, *tail_w, *tail_b;
    int *meta;
    float *eaw, *ebw, *leafTA, *leafTB, *bfused, *fn_pre, *ptr_pre, *h, *out;
};

// ---------------------------------------------------------------------------
// K1: bid0 = fast build (wave-shfl scans, ~7 barriers total);
//     bid1 = all small precompute tables; bid>=2 = ptr_pre GEMV (lane=row).
// ---------------------------------------------------------------------------
__global__ __launch_bounds__(1024) void k1_kernel(KParams p)
{
    const int bid = blockIdx.x;
    const int t   = threadIdx.x;

    if (bid == 0) {
        // ================= structure build =================
        __shared__ unsigned long long wtot64[16];
        __shared__ int wtoti[16];
        __shared__ int sb[5];
        __shared__ int sdeg[N_PER];   // 16 KB

        int lane = t & 63, wid = t >> 6;
        int i0 = 4 * t;
        int hgt[4], par[4];
        unsigned long long cnt = 0;
        #pragma unroll
        for (int q = 0; q < 4; ++q) {
            int i = i0 + q;
            hgt[q] = p.height[i];
            par[q] = p.parent[i];
            if (hgt[q] >= 1 && hgt[q] <= 5) cnt += 1ull << (12 * (hgt[q] - 1));
        }
        unsigned long long inc = cnt;
        #pragma unroll
        for (int off = 1; off < 64; off <<= 1) {
            unsigned long long v = __shfl_up(inc, off, 64);
            if (lane >= off) inc += v;
        }
        if (lane == 63) wtot64[wid] = inc;
        __syncthreads();
        if (t < 16) {
            unsigned long long x = wtot64[t];
            #pragma unroll
            for (int off = 1; off < 16; off <<= 1) {
                unsigned long long v = __shfl_up(x, off, 64);
                if (t >= off) x += v;
            }
            wtot64[t] = x;
        }
        __syncthreads();
        unsigned long long tot = wtot64[15];
        unsigned long long ex  = ((wid > 0) ? wtot64[wid - 1] : 0ull) + inc - cnt;
        if (t == 0) {
            int s = 0;
            for (int l = 0; l < 5; ++l) {
                int c = (int)((tot >> (12 * l)) & 0xFFF);
                p.meta[MH_CNT + l]   = c;
                p.meta[MH_PBASE + l] = s;
                sb[l] = s;
                s += c;
            }
        }
        __syncthreads();
        #pragma unroll
        for (int q = 0; q < 4; ++q) {
            int i = i0 + q, hv = hgt[q];
            if (hv >= 1 && hv <= 5) {
                int l = hv - 1;
                int pos = (int)((ex >> (12 * l)) & 0xFFF);
                ex += 1ull << (12 * l);
                p.meta[OFF_PLIST + sb[l] + pos] = i;
            }
        }
        // degrees (node-indexed)
        #pragma unroll
        for (int q = 0; q < 4; ++q) sdeg[i0 + q] = 0;
        __syncthreads();
        #pragma unroll
        for (int q = 0; q < 4; ++q) {
            int i = i0 + q;
            if (i != 0) atomicAdd(&sdeg[par[q]], 1);
        }
        __syncthreads();
        int d0 = sdeg[i0], d1 = sdeg[i0 + 1], d2 = sdeg[i0 + 2], d3 = sdeg[i0 + 3];
        int s4 = d0 + d1 + d2 + d3;
        int inci = s4;
        #pragma unroll
        for (int off = 1; off < 64; off <<= 1) {
            int v = __shfl_up(inci, off, 64);
            if (lane >= off) inci += v;
        }
        if (lane == 63) wtoti[wid] = inci;
        __syncthreads();
        if (t < 16) {
            int x = wtoti[t];
            #pragma unroll
            for (int off = 1; off < 16; off <<= 1) {
                int v = __shfl_up(x, off, 64);
                if (t >= off) x += v;
            }
            wtoti[t] = x;
        }
        __syncthreads();
        int exi = ((wid > 0) ? wtoti[wid - 1] : 0) + inci - s4;
        int o0 = exi, o1 = exi + d0, o2 = o1 + d1, o3 = o2 + d2;
        p.meta[OFF_COFF + i0]     = o0;
        p.meta[OFF_COFF + i0 + 1] = o1;
        p.meta[OFF_COFF + i0 + 2] = o2;
        p.meta[OFF_COFF + i0 + 3] = o3;
        sdeg[i0] = o0; sdeg[i0 + 1] = o1; sdeg[i0 + 2] = o2; sdeg[i0 + 3] = o3;
        if (t == 1023) p.meta[OFF_COFF + N_PER] = o3 + d3;
        __syncthreads();
        #pragma unroll
        for (int q = 0; q < 4; ++q) {
            int i = i0 + q;
            if (i != 0) {
                int pos = atomicAdd(&sdeg[par[q]], 1);
                p.meta[OFF_CIDX + pos] = i;
            }
        }
    } else if (bid == 1) {
        // ================= table precompute =================
        __shared__ float sWf[32 * 32];   // fused leaf weight W1@W2
        {
            int k = t >> 5, d = t & 31;
            float s = 0.f;
            #pragma unroll
            for (int m = 0; m < 32; ++m)
                s += p.leaf_w1[k * 32 + m] * p.leaf_w2[m * 32 + d];
            sWf[t] = s;
        }
        if (t < 32) {
            float s = p.leaf_b2[t];
            #pragma unroll
            for (int k = 0; k < 32; ++k) s += p.leaf_b1[k] * p.leaf_w2[k * 32 + t];
            p.bfused[t] = s;
        }
        __syncthreads();
        // leafTA/leafTB (fused) and eaw/ebw (node_w halves)
        for (int idx = t; idx < VOCAB * HID; idx += 1024) {
            int v = idx >> 5, d = idx & 31;
            float la = 0.f, lb = 0.f, sa = 0.f, sb2 = 0.f;
            #pragma unroll
            for (int k = 0; k < EMBED; ++k) {
                float e = p.embedding[v * EMBED + k];
                la  += e * sWf[k * 32 + d];
                lb  += e * sWf[(EMBED + k) * 32 + d];
                sa  += e * p.node_w[k * HID + d];
                sb2 += e * p.node_w[(EMBED + k) * HID + d];
            }
            p.leafTA[idx] = la;
            p.leafTB[idx] = lb;
            p.eaw[idx]    = sa;
            p.ebw[idx]    = sb2;
        }
        // fn_pre
        for (int idx = t; idx < BATCH * HID; idx += 1024) {
            int r = idx >> 5, d = idx & 31;
            float s = p.ptr_b[d];
            #pragma unroll
            for (int k = 0; k < NOTE; ++k)
                s += p.first_notes[r * NOTE + k] * p.ptr_w[k * HID + d];
            p.fn_pre[idx] = s;
        }
    } else {
        // ================= ptr_pre GEMV, lane=row =================
        int lane = t & 63;
        int gw = (bid - 2) * 16 + (t >> 6);
        int nw = (gridDim.x - 2) * 16;
        for (int wb = gw; wb < (BATCH * T_LEN) / 64; wb += nw) {
            int row = wb * 64 + lane;
            const float4* lo4 = (const float4*)(p.lstm_out + (size_t)row * LSTM_D);
            float4 v0 = {0,0,0,0}, v1 = v0, v2 = v0, v3 = v0,
                   v4 = v0, v5 = v0, v6 = v0, v7 = v0;
            #pragma unroll
            for (int qq = 0; qq < 16; ++qq) {
                float4 a = lo4[qq];
                #define PMV(CK, KIDX) { \
                    const float4* wr = (const float4*)(p.ptr_w + (NOTE + (KIDX)) * HID); \
                    float4 w; \
                    w = wr[0]; v0.x += (CK)*w.x; v0.y += (CK)*w.y; v0.z += (CK)*w.z; v0.w += (CK)*w.w; \
                    w = wr[1]; v1.x += (CK)*w.x; v1.y += (CK)*w.y; v1.z += (CK)*w.z; v1.w += (CK)*w.w; \
                    w = wr[2]; v2.x += (CK)*w.x; v2.y += (CK)*w.y; v2.z += (CK)*w.z; v2.w += (CK)*w.w; \
                    w = wr[3]; v3.x += (CK)*w.x; v3.y += (CK)*w.y; v3.z += (CK)*w.z; v3.w += (CK)*w.w; \
                    w = wr[4]; v4.x += (CK)*w.x; v4.y += (CK)*w.y; v4.z += (CK)*w.z; v4.w += (CK)*w.w; \
                    w = wr[5]; v5.x += (CK)*w.x; v5.y += (CK)*w.y; v5.z += (CK)*w.z; v5.w += (CK)*w.w; \
                    w = wr[6]; v6.x += (CK)*w.x; v6.y += (CK)*w.y; v6.z += (CK)*w.z; v6.w += (CK)*w.w; \
                    w = wr[7]; v7.x += (CK)*w.x; v7.y += (CK)*w.y; v7.z += (CK)*w.z; v7.w += (CK)*w.w; }
                PMV(a.x, 4 * qq + 0)
                PMV(a.y, 4 * qq + 1)
                PMV(a.z, 4 * qq + 2)
                PMV(a.w, 4 * qq + 3)
            }
            float4* o = (float4*)(p.ptr_pre + (size_t)row * HID);
            o[0] = v0; o[1] = v1; o[2] = v2; o[3] = v3;
            o[4] = v4; o[5] = v5; o[6] = v6; o[7] = v7;
        }
    }
}

// ---------------------------------------------------------------------------
// K2: leaf + ptr rows, lane=tree, pure gathers (no matvec, no shuffles).
//     leaf: h = leafTA[ta] + leafTB[tb] + bfused (leaf MLP is linear!)
//     ptr:  h = fn_pre[tree] + ptr_pre[tree][tt]
// ---------------------------------------------------------------------------
__global__ __launch_bounds__(256) void leafptr_kernel(KParams p)
{
    int wave  = (blockIdx.x * 256 + threadIdx.x) >> 6;
    int nwave = (gridDim.x * 256) >> 6;
    int lane  = threadIdx.x & 63;

    int tot = N_PER * 4;
    const float4* BF = (const float4*)p.bfused;
    for (int i = wave; i < tot; i += nwave) {
        int node = i >> 2, chunk = i & 3;
        if (p.height[node] != 0) continue;          // wave-uniform skip
        int tree = chunk * 64 + lane;
        int gn = tree * N_PER + node;
        float4* o = (float4*)(p.h + (size_t)node * HSTR + tree * HID);
        if (p.kind[node] == 0) {
            int ta = p.tok_a[gn], tb = p.tok_b[gn];
            const float4* A = (const float4*)(p.leafTA + ta * HID);
            const float4* B = (const float4*)(p.leafTB + tb * HID);
            #pragma unroll
            for (int q = 0; q < 8; ++q) {
                float4 a = A[q], b = B[q], c = BF[q];
                float4 r;
                r.x = a.x + b.x + c.x; r.y = a.y + b.y + c.y;
                r.z = a.z + b.z + c.z; r.w = a.w + b.w + c.w;
                o[q] = r;
            }
        } else {
            int tt = p.ptr_time[gn];
            const float4* F = (const float4*)(p.fn_pre + tree * HID);
            const float4* Q = (const float4*)(p.ptr_pre + ((size_t)tree * T_LEN + tt) * HID);
            #pragma unroll
            for (int q = 0; q < 8; ++q) {
                float4 f = F[q], g = Q[q];
                float4 r;
                r.x = f.x + g.x; r.y = f.y + g.y;
                r.z = f.z + g.z; r.w = f.w + g.w;
                o[q] = r;
            }
        }
    }
}

// ---------------------------------------------------------------------------
// K3..K7: level pass, lane=tree (wave64 = one parent x 64 trees), identity
// slots, node-indexed CSR. No shuffles, no LDS.
// ---------------------------------------------------------------------------
__global__ __launch_bounds__(256) void level_kernel(KParams p, int l)
{
    const int* meta = p.meta;
    int cnt = meta[MH_CNT + l];
    int pb  = meta[MH_PBASE + l];
    const int* PL   = meta + OFF_PLIST;
    const int* CO   = meta + OFF_COFF;
    const int* CIDX = meta + OFF_CIDX;
    const float* W  = p.node_w + 2 * EMBED * HID;   // [32][32]

    int wave   = (blockIdx.x * 256 + threadIdx.x) >> 6;
    int nwave  = (gridDim.x * 256) >> 6;
    int lane64 = threadIdx.x & 63;

    int tot = cnt * 4;
    for (int i = wave; i < tot; i += nwave) {
        int rr = i >> 2, chunk = i & 3;
        int tree = chunk * 64 + lane64;
        int node = PL[pb + rr];
        int e = CO[node], e1 = CO[node + 1];

        float4 c0 = {0,0,0,0}, c1 = c0, c2 = c0, c3 = c0,
               c4 = c0, c5 = c0, c6 = c0, c7 = c0;
        for (int c = e; c < e1; ++c) {
            int cn = CIDX[c];
            const float4* row = (const float4*)(p.h + (size_t)cn * HSTR + tree * HID);
            float4 x;
            x = row[0]; c0.x += x.x; c0.y += x.y; c0.z += x.z; c0.w += x.w;
            x = row[1]; c1.x += x.x; c1.y += x.y; c1.z += x.z; c1.w += x.w;
            x = row[2]; c2.x += x.x; c2.y += x.y; c2.z += x.z; c2.w += x.w;
            x = row[3]; c3.x += x.x; c3.y += x.y; c3.z += x.z; c3.w += x.w;
            x = row[4]; c4.x += x.x; c4.y += x.y; c4.z += x.z; c4.w += x.w;
            x = row[5]; c5.x += x.x; c5.y += x.y; c5.z += x.z; c5.w += x.w;
            x = row[6]; c6.x += x.x; c6.y += x.y; c6.z += x.z; c6.w += x.w;
            x = row[7]; c7.x += x.x; c7.y += x.y; c7.z += x.z; c7.w += x.w;
        }

        int gn = tree * N_PER + node;
        int ta = p.tok_a[gn], tb = p.tok_b[gn];
        const float4* A  = (const float4*)(p.eaw + ta * HID);
        const float4* B  = (const float4*)(p.ebw + tb * HID);
        const float4* NB = (const float4*)p.node_b;
        float4 v0, v1, v2, v3, v4, v5, v6, v7;
        #define INITV(VQ, Q) { float4 nb = NB[Q], a = A[Q], b = B[Q]; \
            VQ.x = nb.x + a.x + b.x; VQ.y = nb.y + a.y + b.y; \
            VQ.z = nb.z + a.z + b.z; VQ.w = nb.w + a.w + b.w; }
        INITV(v0,0) INITV(v1,1) INITV(v2,2) INITV(v3,3)
        INITV(v4,4) INITV(v5,5) INITV(v6,6) INITV(v7,7)

        #define MV(CK, KIDX) { \
            const float4* wr = (const float4*)(W + (KIDX) * HID); float4 w; \
            w = wr[0]; v0.x += (CK)*w.x; v0.y += (CK)*w.y; v0.z += (CK)*w.z; v0.w += (CK)*w.w; \
            w = wr[1]; v1.x += (CK)*w.x; v1.y += (CK)*w.y; v1.z += (CK)*w.z; v1.w += (CK)*w.w; \
            w = wr[2]; v2.x += (CK)*w.x; v2.y += (CK)*w.y; v2.z += (CK)*w.z; v2.w += (CK)*w.w; \
            w = wr[3]; v3.x += (CK)*w.x; v3.y += (CK)*w.y; v3.z += (CK)*w.z; v3.w += (CK)*w.w; \
            w = wr[4]; v4.x += (CK)*w.x; v4.y += (CK)*w.y; v4.z += (CK)*w.z; v4.w += (CK)*w.w; \
            w = wr[5]; v5.x += (CK)*w.x; v5.y += (CK)*w.y; v5.z += (CK)*w.z; v5.w += (CK)*w.w; \
            w = wr[6]; v6.x += (CK)*w.x; v6.y += (CK)*w.y; v6.z += (CK)*w.z; v6.w += (CK)*w.w; \
            w = wr[7]; v7.x += (CK)*w.x; v7.y += (CK)*w.y; v7.z += (CK)*w.z; v7.w += (CK)*w.w; }
        MV(c0.x, 0)  MV(c0.y, 1)  MV(c0.z, 2)  MV(c0.w, 3)
        MV(c1.x, 4)  MV(c1.y, 5)  MV(c1.z, 6)  MV(c1.w, 7)
        MV(c2.x, 8)  MV(c2.y, 9)  MV(c2.z, 10) MV(c2.w, 11)
        MV(c3.x, 12) MV(c3.y, 13) MV(c3.z, 14) MV(c3.w, 15)
        MV(c4.x, 16) MV(c4.y, 17) MV(c4.z, 18) MV(c4.w, 19)
        MV(c5.x, 20) MV(c5.y, 21) MV(c5.z, 22) MV(c5.w, 23)
        MV(c6.x, 24) MV(c6.y, 25) MV(c6.z, 26) MV(c6.w, 27)
        MV(c7.x, 28) MV(c7.y, 29) MV(c7.z, 30) MV(c7.w, 31)

        float4* o = (float4*)(p.h + (size_t)node * HSTR + tree * HID);
        #define STR(VQ, Q) { VQ.x = fmaxf(VQ.x, 0.f); VQ.y = fmaxf(VQ.y, 0.f); \
            VQ.z = fmaxf(VQ.z, 0.f); VQ.w = fmaxf(VQ.w, 0.f); o[Q] = VQ; }
        STR(v0,0) STR(v1,1) STR(v2,2) STR(v3,3)
        STR(v4,4) STR(v5,5) STR(v6,6) STR(v7,7)
    }
}

// ---------------------------------------------------------------------------
// K8: one block per tree: gather root children (CSR of node 0), LDS reduce,
// finish root h, FF head -> out[tree].
// ---------------------------------------------------------------------------
__global__ __launch_bounds__(256) void root_final_kernel(KParams p)
{
    __shared__ float red[8][HID];
    const int* CO   = p.meta + OFF_COFF;
    const int* CIDX = p.meta + OFF_CIDX;
    int e = CO[0], e1 = CO[1];   // root = node 0

    int tree = blockIdx.x;
    int grp  = threadIdx.x >> 5;
    int lane = threadIdx.x & 31;

    float part = 0.f;
    for (int c = e + grp; c < e1; c += 8)
        part += p.h[(size_t)CIDX[c] * HSTR + tree * HID + lane];
    red[grp][lane] = part;
    __syncthreads();

    if (grp == 0) {
        float csum = red[0][lane];
        #pragma unroll
        for (int g = 1; g < 8; ++g) csum += red[g][lane];

        int gn = tree * N_PER;   // root node 0
        int ta = p.tok_a[gn], tb = p.tok_b[gn];
        float v = p.node_b[lane] + p.eaw[ta * HID + lane] + p.ebw[tb * HID + lane];
        #pragma unroll
        for (int k = 0; k < HID; ++k)
            v += __shfl(csum, k, 32) * p.node_w[(2 * EMBED + k) * HID + lane];
        v = fmaxf(v, 0.f);

        float f1 = p.ff_b1[lane];
        #pragma unroll
        for (int k = 0; k < HID; ++k) f1 += __shfl(v, k, 32) * p.ff_w1[k * HID + lane];
        float f2 = p.ff_b2[lane];
        #pragma unroll
        for (int k = 0; k < HID; ++k) f2 += __shfl(f1, k, 32) * p.ff_w2[k * HID + lane];

        float c2 = f2 * p.tail_w[lane];
        #pragma unroll
        for (int off = 16; off > 0; off >>= 1) c2 += __shfl_down(c2, off, 32);
        if (lane == 0) p.out[tree] = c2 + p.tail_b[0];
    }
}

extern "C" void kernel_launch(void* const* d_in, const int* in_sizes, int n_in,
                              void* d_out, int out_size, void* d_ws, size_t ws_size,
                              hipStream_t stream) {
    char* ws = (char*)d_ws;
    KParams prm;
    prm.kind        = (const int*)d_in[0];
    prm.height      = (const int*)d_in[1];
    prm.parent      = (const int*)d_in[2];
    prm.tok_a       = (const int*)d_in[3];
    prm.tok_b       = (const int*)d_in[4];
    prm.ptr_time    = (const int*)d_in[5];
    prm.first_notes = (const float*)d_in[6];
    prm.lstm_out    = (const float*)d_in[7];
    prm.embedding   = (const float*)d_in[8];
    prm.leaf_w1     = (const float*)d_in[9];
    prm.leaf_b1     = (const float*)d_in[10];
    prm.leaf_w2     = (const float*)d_in[11];
    prm.leaf_b2     = (const float*)d_in[12];
    prm.node_w      = (const float*)d_in[13];
    prm.node_b      = (const float*)d_in[14];
    prm.ptr_w       = (const float*)d_in[15];
    prm.ptr_b       = (const float*)d_in[16];
    prm.ff_w1       = (const float*)d_in[17];
    prm.ff_b1       = (const float*)d_in[18];
    prm.ff_w2       = (const float*)d_in[19];
    prm.ff_b2       = (const float*)d_in[20];
    prm.tail_w      = (const float*)d_in[21];
    prm.tail_b      = (const float*)d_in[22];
    prm.meta    = (int*)ws;
    prm.eaw     = (float*)(ws + EAW_BYTE);
    prm.ebw     = (float*)(ws + EBW_BYTE);
    prm.leafTA  = (float*)(ws + LEAFTA_BYTE);
    prm.leafTB  = (float*)(ws + LEAFTB_BYTE);
    prm.bfused  = (float*)(ws + BF_BYTE);
    prm.fn_pre  = (float*)(ws + FNPRE_BYTE);
    prm.ptr_pre = (float*)(ws + PTRPRE_BYTE);
    prm.h       = (float*)(ws + H_BYTE);
    prm.out     = (float*)d_out;

    k1_kernel<<<64, 1024, 0, stream>>>(prm);
    leafptr_kernel<<<512, 256, 0, stream>>>(prm);
    for (int l = 0; l < 5; ++l)
        level_kernel<<<1024, 256, 0, stream>>>(prm, l);
    root_final_kernel<<<BATCH, 256, 0, stream>>>(prm);
}

// Round 11
// 435.078 us; speedup vs baseline: 1.2756x; 1.2756x over previous
//
#include <hip/hip_runtime.h>

// Problem constants (fixed by the reference's setup_inputs)
#define BATCH   256
#define N_PER   4096
#define EMBED   16
#define HID     32
#define NOTE    64
#define LSTM_D  64
#define T_LEN   128
#define VOCAB   200
#define HSTR    (BATCH * HID)     // floats per node row-group (tree-inner layout)

// meta header (ints)
#define MH_CNT   0    // [0..4] internal count at level 1..5
#define MH_PBASE 5    // [5..9] PLIST base of level 1..5
#define MH_K0    10   // kind-0 leaf count
#define MH_K1    11   // kind-1 ptr count
// meta arrays (ints)
#define OFF_PLIST 64
#define OFF_COFF  (OFF_PLIST + N_PER)      // N_PER+1, node-indexed
#define OFF_CIDX  (OFF_COFF + N_PER + 1)   // child node ids
#define OFF_K0N   (OFF_CIDX + N_PER)
#define OFF_K1N   (OFF_K0N + N_PER)
// ws byte offsets
#define EAW_BYTE    (1024 * 1024)          // [VOCAB][HID]
#define EBW_BYTE    (EAW_BYTE + 32 * 1024)
#define LEAFTA_BYTE (EAW_BYTE + 64 * 1024)
#define LEAFTB_BYTE (EAW_BYTE + 96 * 1024)
#define BF_BYTE     (EAW_BYTE + 128 * 1024)
#define FNPRE_BYTE  (1536 * 1024)          // [BATCH][HID]
#define PTRPRE_BYTE (2ull * 1024 * 1024)   // [BATCH*T_LEN][HID] = 4 MB
#define TOKU_BYTE   (6ull * 1024 * 1024)   // [N_PER][BATCH] u16 = 2 MB
#define H_BYTE      (8ull * 1024 * 1024)   // [node][BATCH][HID] = 134 MB

struct KParams {
    const int *kind, *height, *parent, *tok_a, *tok_b, *ptr_time;
    const float *first_notes, *lstm_out, *embedding;
    const float *leaf_w1, *leaf_b1, *leaf_w2, *leaf_b2;
    const float *node_w, *node_b, *ptr_w, *ptr_b;
    const float *ff_w1, *ff_b1, *ff_w2, *ff_b2, *tail_w, *tail_b;
    int *meta;
    unsigned short *toku;
    float *eaw, *ebw, *leafTA, *leafTB, *bfused, *fn_pre, *ptr_pre, *h, *out;
};

// ---------------------------------------------------------------------------
// K1: structure build, 1 block x 1024, wave-shfl scans (few barriers).
// Outputs: level counts/bases + PLIST, K0N/K1N lists, node-indexed CSR.
// ---------------------------------------------------------------------------
__global__ __launch_bounds__(1024) void build_kernel(KParams p)
{
    __shared__ unsigned long long wtot64[16];
    __shared__ unsigned int wtotl[16];
    __shared__ int wtoti[16];
    __shared__ int sb[5];
    __shared__ int sdeg[N_PER];   // 16 KB

    const int t = threadIdx.x;
    int lane = t & 63, wid = t >> 6;
    int i0 = 4 * t;
    int hgt[4], par[4], knd[4];
    unsigned long long cnt = 0;
    unsigned int lcnt = 0;
    #pragma unroll
    for (int q = 0; q < 4; ++q) {
        int i = i0 + q;
        hgt[q] = p.height[i];
        par[q] = p.parent[i];
        knd[q] = p.kind[i];
        if (hgt[q] >= 1 && hgt[q] <= 5) cnt += 1ull << (12 * (hgt[q] - 1));
        else if (hgt[q] == 0) lcnt += (knd[q] == 0) ? 1u : 0x10000u;
    }
    // --- scan 1: levels (u64, 12-bit fields) ---
    unsigned long long inc = cnt;
    #pragma unroll
    for (int off = 1; off < 64; off <<= 1) {
        unsigned long long v = __shfl_up(inc, off, 64);
        if (lane >= off) inc += v;
    }
    if (lane == 63) wtot64[wid] = inc;
    __syncthreads();
    if (t < 16) {
        unsigned long long x = wtot64[t];
        #pragma unroll
        for (int off = 1; off < 16; off <<= 1) {
            unsigned long long v = __shfl_up(x, off, 64);
            if (t >= off) x += v;
        }
        wtot64[t] = x;
    }
    __syncthreads();
    unsigned long long tot = wtot64[15];
    unsigned long long ex  = ((wid > 0) ? wtot64[wid - 1] : 0ull) + inc - cnt;
    if (t == 0) {
        int s = 0;
        for (int l = 0; l < 5; ++l) {
            int c = (int)((tot >> (12 * l)) & 0xFFF);
            p.meta[MH_CNT + l]   = c;
            p.meta[MH_PBASE + l] = s;
            sb[l] = s;
            s += c;
        }
    }
    __syncthreads();
    #pragma unroll
    for (int q = 0; q < 4; ++q) {
        int i = i0 + q, hv = hgt[q];
        if (hv >= 1 && hv <= 5) {
            int l = hv - 1;
            int pos = (int)((ex >> (12 * l)) & 0xFFF);
            ex += 1ull << (12 * l);
            p.meta[OFF_PLIST + sb[l] + pos] = i;
        }
    }
    // --- scan 2: leaves (u32: k0 low16, k1 high16) ---
    unsigned int incl = lcnt;
    #pragma unroll
    for (int off = 1; off < 64; off <<= 1) {
        unsigned int v = __shfl_up(incl, off, 64);
        if (lane >= off) incl += v;
    }
    if (lane == 63) wtotl[wid] = incl;
    __syncthreads();
    if (t < 16) {
        unsigned int x = wtotl[t];
        #pragma unroll
        for (int off = 1; off < 16; off <<= 1) {
            unsigned int v = __shfl_up(x, off, 64);
            if (t >= off) x += v;
        }
        wtotl[t] = x;
    }
    __syncthreads();
    unsigned int ltot = wtotl[15];
    unsigned int exl  = ((wid > 0) ? wtotl[wid - 1] : 0u) + incl - lcnt;
    if (t == 0) { p.meta[MH_K0] = (int)(ltot & 0xFFFF); p.meta[MH_K1] = (int)(ltot >> 16); }
    #pragma unroll
    for (int q = 0; q < 4; ++q) {
        int i = i0 + q;
        if (hgt[q] == 0) {
            if (knd[q] == 0) { p.meta[OFF_K0N + (exl & 0xFFFF)] = i; exl += 1u; }
            else             { p.meta[OFF_K1N + (exl >> 16)]    = i; exl += 0x10000u; }
        }
    }
    // --- degrees + CSR ---
    #pragma unroll
    for (int q = 0; q < 4; ++q) sdeg[i0 + q] = 0;
    __syncthreads();
    #pragma unroll
    for (int q = 0; q < 4; ++q) {
        int i = i0 + q;
        if (i != 0) atomicAdd(&sdeg[par[q]], 1);
    }
    __syncthreads();
    int d0 = sdeg[i0], d1 = sdeg[i0 + 1], d2 = sdeg[i0 + 2], d3 = sdeg[i0 + 3];
    int s4 = d0 + d1 + d2 + d3;
    int inci = s4;
    #pragma unroll
    for (int off = 1; off < 64; off <<= 1) {
        int v = __shfl_up(inci, off, 64);
        if (lane >= off) inci += v;
    }
    if (lane == 63) wtoti[wid] = inci;
    __syncthreads();
    if (t < 16) {
        int x = wtoti[t];
        #pragma unroll
        for (int off = 1; off < 16; off <<= 1) {
            int v = __shfl_up(x, off, 64);
            if (t >= off) x += v;
        }
        wtoti[t] = x;
    }
    __syncthreads();
    int exi = ((wid > 0) ? wtoti[wid - 1] : 0) + inci - s4;
    int o0 = exi, o1 = exi + d0, o2 = o1 + d1, o3 = o2 + d2;
    p.meta[OFF_COFF + i0]     = o0;
    p.meta[OFF_COFF + i0 + 1] = o1;
    p.meta[OFF_COFF + i0 + 2] = o2;
    p.meta[OFF_COFF + i0 + 3] = o3;
    sdeg[i0] = o0; sdeg[i0 + 1] = o1; sdeg[i0 + 2] = o2; sdeg[i0 + 3] = o3;
    if (t == 1023) p.meta[OFF_COFF + N_PER] = o3 + d3;
    __syncthreads();
    #pragma unroll
    for (int q = 0; q < 4; ++q) {
        int i = i0 + q;
        if (i != 0) {
            int pos = atomicAdd(&sdeg[par[q]], 1);
            p.meta[OFF_CIDX + pos] = i;
        }
    }
}

// ---------------------------------------------------------------------------
// K2 prep, 512 blocks x 256:
//  bid 0..255   : tok transpose tiles -> toku[node][tree] = (ta<<8)|tb (u16)
//  bid 256..319 : ptr_pre GEMV, lane=row (wave64 = 64 consecutive rows)
//  bid 320..511 : eaw/ebw/leafTA/leafTB tables + bfused + fn_pre
// ---------------------------------------------------------------------------
__global__ __launch_bounds__(256) void prep_kernel(KParams p)
{
    const int bid = blockIdx.x;
    const int t   = threadIdx.x;

    if (bid < 256) {
        // 64-node x 64-tree tile transpose via LDS
        __shared__ unsigned int tile[64][65];
        int ntile = bid >> 2, ttile = bid & 3;
        int node0 = ntile * 64, tree0 = ttile * 64;
        int tx = t & 63, tw = t >> 6;
        #pragma unroll
        for (int rr = 0; rr < 16; ++rr) {
            int tree_in = rr * 4 + tw;
            int gn = (tree0 + tree_in) * N_PER + node0 + tx;
            unsigned int v = ((unsigned int)p.tok_a[gn] << 8) | (unsigned int)p.tok_b[gn];
            tile[tx][tree_in] = v;
        }
        __syncthreads();
        #pragma unroll
        for (int rr = 0; rr < 16; ++rr) {
            int node_in = rr * 4 + tw;
            p.toku[(node0 + node_in) * BATCH + tree0 + tx] = (unsigned short)tile[node_in][tx];
        }
    } else if (bid < 320) {
        // ptr_pre: row = lane, 64 rows per wave, 8 KB coalesced lstm reads
        int lane = t & 63;
        int gw = (bid - 256) * 4 + (t >> 6);
        const int nw = 64 * 4;
        for (int wb = gw; wb < (BATCH * T_LEN) / 64; wb += nw) {
            int row = wb * 64 + lane;
            const float4* lo4 = (const float4*)(p.lstm_out + (size_t)row * LSTM_D);
            float4 v0 = {0,0,0,0}, v1 = v0, v2 = v0, v3 = v0,
                   v4 = v0, v5 = v0, v6 = v0, v7 = v0;
            #pragma unroll
            for (int qq = 0; qq < 16; ++qq) {
                float4 a = lo4[qq];
                #define PMV(CK, KIDX) { \
                    const float4* wr = (const float4*)(p.ptr_w + (NOTE + (KIDX)) * HID); \
                    float4 w; \
                    w = wr[0]; v0.x += (CK)*w.x; v0.y += (CK)*w.y; v0.z += (CK)*w.z; v0.w += (CK)*w.w; \
                    w = wr[1]; v1.x += (CK)*w.x; v1.y += (CK)*w.y; v1.z += (CK)*w.z; v1.w += (CK)*w.w; \
                    w = wr[2]; v2.x += (CK)*w.x; v2.y += (CK)*w.y; v2.z += (CK)*w.z; v2.w += (CK)*w.w; \
                    w = wr[3]; v3.x += (CK)*w.x; v3.y += (CK)*w.y; v3.z += (CK)*w.z; v3.w += (CK)*w.w; \
                    w = wr[4]; v4.x += (CK)*w.x; v4.y += (CK)*w.y; v4.z += (CK)*w.z; v4.w += (CK)*w.w; \
                    w = wr[5]; v5.x += (CK)*w.x; v5.y += (CK)*w.y; v5.z += (CK)*w.z; v5.w += (CK)*w.w; \
                    w = wr[6]; v6.x += (CK)*w.x; v6.y += (CK)*w.y; v6.z += (CK)*w.z; v6.w += (CK)*w.w; \
                    w = wr[7]; v7.x += (CK)*w.x; v7.y += (CK)*w.y; v7.z += (CK)*w.z; v7.w += (CK)*w.w; }
                PMV(a.x, 4 * qq + 0)
                PMV(a.y, 4 * qq + 1)
                PMV(a.z, 4 * qq + 2)
                PMV(a.w, 4 * qq + 3)
            }
            float4* o = (float4*)(p.ptr_pre + (size_t)row * HID);
            o[0] = v0; o[1] = v1; o[2] = v2; o[3] = v3;
            o[4] = v4; o[5] = v5; o[6] = v6; o[7] = v7;
        }
    } else {
        // tables + fn_pre (192 blocks)
        __shared__ float sWf[32 * 32];   // fused leaf weight W1@W2
        for (int idx = t; idx < 1024; idx += 256) {
            int k = idx >> 5, d = idx & 31;
            float s = 0.f;
            #pragma unroll
            for (int m = 0; m < 32; ++m)
                s += p.leaf_w1[k * 32 + m] * p.leaf_w2[m * 32 + d];
            sWf[idx] = s;
        }
        __syncthreads();
        if (bid == 320 && t < 32) {
            float s = p.leaf_b2[t];
            #pragma unroll
            for (int k = 0; k < 32; ++k) s += p.leaf_b1[k] * p.leaf_w2[k * 32 + t];
            p.bfused[t] = s;
        }
        int wt = (bid - 320) * 256 + t;
        const int nw = 192 * 256;
        for (int idx = wt; idx < VOCAB * HID; idx += nw) {
            int v = idx >> 5, d = idx & 31;
            float la = 0.f, lb = 0.f, sa = 0.f, sb2 = 0.f;
            #pragma unroll
            for (int k = 0; k < EMBED; ++k) {
                float e = p.embedding[v * EMBED + k];
                la  += e * sWf[k * 32 + d];
                lb  += e * sWf[(EMBED + k) * 32 + d];
                sa  += e * p.node_w[k * HID + d];
                sb2 += e * p.node_w[(EMBED + k) * HID + d];
            }
            p.leafTA[idx] = la;
            p.leafTB[idx] = lb;
            p.eaw[idx]    = sa;
            p.ebw[idx]    = sb2;
        }
        for (int idx = wt; idx < BATCH * HID; idx += nw) {
            int r = idx >> 5, d = idx & 31;
            float s = p.ptr_b[d];
            #pragma unroll
            for (int k = 0; k < NOTE; ++k)
                s += p.first_notes[r * NOTE + k] * p.ptr_w[k * HID + d];
            p.fn_pre[idx] = s;
        }
    }
}

// ---------------------------------------------------------------------------
// K3: leaf + ptr rows via compact lists, group-of-32 (lane = hid).
// leaf: h = leafTA[ta] + leafTB[tb] + bfused (leaf MLP is linear).
// ---------------------------------------------------------------------------
__global__ __launch_bounds__(256) void leafptr_kernel(KParams p)
{
    const int* meta = p.meta;
    int lane = threadIdx.x & 31;
    int ggrp = (blockIdx.x * 256 + threadIdx.x) >> 5;
    int ngrp = (gridDim.x * 256) >> 5;

    int c0 = meta[MH_K0];
    const int* K0N = meta + OFF_K0N;
    float bf = p.bfused[lane];
    int tot = c0 * BATCH;
    for (int i = ggrp; i < tot; i += ngrp) {
        int j = i >> 8, tree = i & 255;
        int node = K0N[j];
        int gn = tree * N_PER + node;
        int ta = p.tok_a[gn], tb = p.tok_b[gn];
        float v = bf + p.leafTA[ta * HID + lane] + p.leafTB[tb * HID + lane];
        p.h[(size_t)node * HSTR + tree * HID + lane] = v;
    }

    int c1 = meta[MH_K1];
    const int* K1N = meta + OFF_K1N;
    int tot1 = c1 * BATCH;
    for (int i = ggrp; i < tot1; i += ngrp) {
        int j = i >> 8, tree = i & 255;
        int node = K1N[j];
        int gn = tree * N_PER + node;
        int tt = p.ptr_time[gn];
        float v = p.fn_pre[tree * HID + lane]
                + p.ptr_pre[((size_t)tree * T_LEN + tt) * HID + lane];
        p.h[(size_t)node * HSTR + tree * HID + lane] = v;
    }
}

// ---------------------------------------------------------------------------
// K4..K8: level pass, lane=tree (wave64 = one parent x 64 trees).
// 4-deep child-load pipelining; W in LDS (lgkmcnt, keeps vmcnt for gathers);
// coalesced toku read.
// ---------------------------------------------------------------------------
__global__ __launch_bounds__(256) void level_kernel(KParams p, int l)
{
    __shared__ float4 sW[32 * 8];    // node_w[32:64] rows as float4
    {
        const float4* Wg = (const float4*)(p.node_w + 2 * EMBED * HID);
        for (int i = threadIdx.x; i < 256; i += 256) sW[i] = Wg[i];
    }
    __syncthreads();

    const int* meta = p.meta;
    int cnt = meta[MH_CNT + l];
    int pb  = meta[MH_PBASE + l];
    const int* PL   = meta + OFF_PLIST;
    const int* CO   = meta + OFF_COFF;
    const int* CIDX = meta + OFF_CIDX;

    int wave   = (blockIdx.x * 256 + threadIdx.x) >> 6;
    int nwave  = (gridDim.x * 256) >> 6;
    int lane64 = threadIdx.x & 63;

    int tot = cnt * 4;
    for (int i = wave; i < tot; i += nwave) {
        int rr = i >> 2, chunk = i & 3;
        int tree = chunk * 64 + lane64;
        int node = PL[pb + rr];
        int e = CO[node], e1 = CO[node + 1];

        float cs[32];
        #pragma unroll
        for (int k = 0; k < 32; ++k) cs[k] = 0.f;

        int c = e;
        for (; c + 3 < e1; c += 4) {
            const float4* r0 = (const float4*)(p.h + (size_t)CIDX[c]     * HSTR + tree * HID);
            const float4* r1 = (const float4*)(p.h + (size_t)CIDX[c + 1] * HSTR + tree * HID);
            const float4* r2 = (const float4*)(p.h + (size_t)CIDX[c + 2] * HSTR + tree * HID);
            const float4* r3 = (const float4*)(p.h + (size_t)CIDX[c + 3] * HSTR + tree * HID);
            #pragma unroll
            for (int q = 0; q < 8; ++q) {
                float4 a = r0[q], b = r1[q], x = r2[q], y = r3[q];
                cs[4*q+0] += (a.x + b.x) + (x.x + y.x);
                cs[4*q+1] += (a.y + b.y) + (x.y + y.y);
                cs[4*q+2] += (a.z + b.z) + (x.z + y.z);
                cs[4*q+3] += (a.w + b.w) + (x.w + y.w);
            }
        }
        for (; c < e1; ++c) {
            const float4* r0 = (const float4*)(p.h + (size_t)CIDX[c] * HSTR + tree * HID);
            #pragma unroll
            for (int q = 0; q < 8; ++q) {
                float4 a = r0[q];
                cs[4*q+0] += a.x; cs[4*q+1] += a.y; cs[4*q+2] += a.z; cs[4*q+3] += a.w;
            }
        }

        unsigned int tku = p.toku[node * BATCH + tree];
        int ta = (int)(tku >> 8), tb = (int)(tku & 255u);
        const float4* A  = (const float4*)(p.eaw + ta * HID);
        const float4* B  = (const float4*)(p.ebw + tb * HID);
        const float4* NB = (const float4*)p.node_b;
        float4 v[8];
        #pragma unroll
        for (int q = 0; q < 8; ++q) {
            float4 nb = NB[q], a = A[q], b = B[q];
            v[q].x = nb.x + a.x + b.x; v[q].y = nb.y + a.y + b.y;
            v[q].z = nb.z + a.z + b.z; v[q].w = nb.w + a.w + b.w;
        }
        #pragma unroll
        for (int k = 0; k < 32; ++k) {
            float ck = cs[k];
            #pragma unroll
            for (int q = 0; q < 8; ++q) {
                float4 w = sW[k * 8 + q];
                v[q].x += ck * w.x; v[q].y += ck * w.y;
                v[q].z += ck * w.z; v[q].w += ck * w.w;
            }
        }
        float4* o = (float4*)(p.h + (size_t)node * HSTR + tree * HID);
        #pragma unroll
        for (int q = 0; q < 8; ++q) {
            float4 x = v[q];
            x.x = fmaxf(x.x, 0.f); x.y = fmaxf(x.y, 0.f);
            x.z = fmaxf(x.z, 0.f); x.w = fmaxf(x.w, 0.f);
            o[q] = x;
        }
    }
}

// ---------------------------------------------------------------------------
// K9: one block per tree: 4-deep root child gather, LDS reduce, finish root,
// FF head -> out[tree].
// ---------------------------------------------------------------------------
__global__ __launch_bounds__(256) void root_final_kernel(KParams p)
{
    __shared__ float red[8][HID];
    const int* CO   = p.meta + OFF_COFF;
    const int* CIDX = p.meta + OFF_CIDX;
    int e = CO[0], e1 = CO[1];   // root = node 0

    int tree = blockIdx.x;
    int grp  = threadIdx.x >> 5;
    int lane = threadIdx.x & 31;

    float part = 0.f;
    int c = e + grp;
    for (; c + 24 < e1; c += 32) {
        float a = p.h[(size_t)CIDX[c]      * HSTR + tree * HID + lane];
        float b = p.h[(size_t)CIDX[c + 8]  * HSTR + tree * HID + lane];
        float x = p.h[(size_t)CIDX[c + 16] * HSTR + tree * HID + lane];
        float y = p.h[(size_t)CIDX[c + 24] * HSTR + tree * HID + lane];
        part += (a + b) + (x + y);
    }
    for (; c < e1; c += 8)
        part += p.h[(size_t)CIDX[c] * HSTR + tree * HID + lane];
    red[grp][lane] = part;
    __syncthreads();

    if (grp == 0) {
        float csum = red[0][lane];
        #pragma unroll
        for (int g = 1; g < 8; ++g) csum += red[g][lane];

        int gn = tree * N_PER;   // root node 0
        int ta = p.tok_a[gn], tb = p.tok_b[gn];
        float v = p.node_b[lane] + p.eaw[ta * HID + lane] + p.ebw[tb * HID + lane];
        #pragma unroll
        for (int k = 0; k < HID; ++k)
            v += __shfl(csum, k, 32) * p.node_w[(2 * EMBED + k) * HID + lane];
        v = fmaxf(v, 0.f);

        float f1 = p.ff_b1[lane];
        #pragma unroll
        for (int k = 0; k < HID; ++k) f1 += __shfl(v, k, 32) * p.ff_w1[k * HID + lane];
        float f2 = p.ff_b2[lane];
        #pragma unroll
        for (int k = 0; k < HID; ++k) f2 += __shfl(f1, k, 32) * p.ff_w2[k * HID + lane];

        float c2 = f2 * p.tail_w[lane];
        #pragma unroll
        for (int off = 16; off > 0; off >>= 1) c2 += __shfl_down(c2, off, 32);
        if (lane == 0) p.out[tree] = c2 + p.tail_b[0];
    }
}

extern "C" void kernel_launch(void* const* d_in, const int* in_sizes, int n_in,
                              void* d_out, int out_size, void* d_ws, size_t ws_size,
                              hipStream_t stream) {
    char* ws = (char*)d_ws;
    KParams prm;
    prm.kind        = (const int*)d_in[0];
    prm.height      = (const int*)d_in[1];
    prm.parent      = (const int*)d_in[2];
    prm.tok_a       = (const int*)d_in[3];
    prm.tok_b       = (const int*)d_in[4];
    prm.ptr_time    = (const int*)d_in[5];
    prm.first_notes = (const float*)d_in[6];
    prm.lstm_out    = (const float*)d_in[7];
    prm.embedding   = (const float*)d_in[8];
    prm.leaf_w1     = (const float*)d_in[9];
    prm.leaf_b1     = (const float*)d_in[10];
    prm.leaf_w2     = (const float*)d_in[11];
    prm.leaf_b2     = (const float*)d_in[12];
    prm.node_w      = (const float*)d_in[13];
    prm.node_b      = (const float*)d_in[14];
    prm.ptr_w       = (const float*)d_in[15];
    prm.ptr_b       = (const float*)d_in[16];
    prm.ff_w1       = (const float*)d_in[17];
    prm.ff_b1       = (const float*)d_in[18];
    prm.ff_w2       = (const float*)d_in[19];
    prm.ff_b2       = (const float*)d_in[20];
    prm.tail_w      = (const float*)d_in[21];
    prm.tail_b      = (const float*)d_in[22];
    prm.meta    = (int*)ws;
    prm.toku    = (unsigned short*)(ws + TOKU_BYTE);
    prm.eaw     = (float*)(ws + EAW_BYTE);
    prm.ebw     = (float*)(ws + EBW_BYTE);
    prm.leafTA  = (float*)(ws + LEAFTA_BYTE);
    prm.leafTB  = (float*)(ws + LEAFTB_BYTE);
    prm.bfused  = (float*)(ws + BF_BYTE);
    prm.fn_pre  = (float*)(ws + FNPRE_BYTE);
    prm.ptr_pre = (float*)(ws + PTRPRE_BYTE);
    prm.h       = (float*)(ws + H_BYTE);
    prm.out     = (float*)d_out;

    build_kernel<<<1, 1024, 0, stream>>>(prm);
    prep_kernel<<<512, 256, 0, stream>>>(prm);
    leafptr_kernel<<<512, 256, 0, stream>>>(prm);
    for (int l = 0; l < 5; ++l)
        level_kernel<<<1024, 256, 0, stream>>>(prm, l);
    root_final_kernel<<<BATCH, 256, 0, stream>>>(prm);
}